// Round 22
// baseline (76.145 us; speedup 1.0000x reference)
//
#include <hip/hip_runtime.h>
#include <hip/hip_bf16.h>

typedef __bf16 bf16x8 __attribute__((ext_vector_type(8)));
typedef float  f32x4  __attribute__((ext_vector_type(4)));
typedef float  f32x2  __attribute__((ext_vector_type(2)));

#define B_  32
#define J_  143
#define F_  120
#define D_  256
#define L_  512
#define C_  13
#define M_  4576      // B_*J_
#define MPAD 4736     // padded rows for PXg (74*64)
#define NK  256       // BT col stride (hi-only bf16)
#define CLS 260       // cl row stride (f32)
#define PXS 388       // px LDS row stride (f32)
#define PXG 384       // PXg global row stride (f32)

static __device__ __forceinline__ unsigned short bits(__bf16 h) {
  return __builtin_bit_cast(unsigned short, h);
}

// ---------- prep (552 blocks) — unchanged from R17/R21 ----------
__global__ __launch_bounds__(256) void prep_kernel(
    const float* __restrict__ z, const float* __restrict__ Wl,
    const float* __restrict__ bl, const float* __restrict__ W1,
    const float* __restrict__ gamma, const float* __restrict__ beta,
    const float* __restrict__ b1, const float* __restrict__ fe,
    const float* __restrict__ W2,
    float* __restrict__ base, unsigned short* __restrict__ BT,
    float* __restrict__ bW1, float* __restrict__ Sfe, float* __restrict__ Sfe2,
    unsigned short* __restrict__ W2T, float* __restrict__ P2f) {
  const int t = threadIdx.x, bid = blockIdx.x;
  const int lane = t & 63, wv = t >> 6;
  __shared__ float zs[L_];
  __shared__ float ra[4], rb[4];
  __shared__ float fegl[256], gl2[256];

  if (bid < 32) {
    zs[t]       = z[bid * L_ + t];
    zs[t + 256] = z[bid * L_ + t + 256];
    __syncthreads();
    float acc = 0.f;
    #pragma unroll 32
    for (int k = 0; k < L_; ++k) acc = __builtin_fmaf(zs[k], Wl[k * D_ + t], acc);
    base[bid * D_ + t] = acc + bl[t];
    return;
  }
  if (bid < 432) {
    const int n = bid - 32;
    if (n < 256) {
      const float w1v = W1[t * D_ + n];
      float a = gamma[t] * w1v;
      float b = beta[t] * w1v;
      const float wg = a;
      #pragma unroll
      for (int m = 1; m < 64; m <<= 1) { a += __shfl_xor(a, m); b += __shfl_xor(b, m); }
      if (lane == 0) { ra[wv] = a; rb[wv] = b; }
      __syncthreads();
      const float cs = ra[0] + ra[1] + ra[2] + ra[3];
      if (t == 0) bW1[n] = rb[0] + rb[1] + rb[2] + rb[3] + b1[n];
      const float m = __builtin_fmaf(cs, -1.f / 256.f, wg);
      BT[n * NK + t] = bits((__bf16)m);
    } else if (n < 376) {
      const int f = n - 256;
      const float v = fe[f * D_ + t];
      float a = v, b = v * v;
      #pragma unroll
      for (int m = 1; m < 64; m <<= 1) { a += __shfl_xor(a, m); b += __shfl_xor(b, m); }
      if (lane == 0) { ra[wv] = a; rb[wv] = b; }
      __syncthreads();
      if (t == 0) {
        Sfe[f]  = ra[0] + ra[1] + ra[2] + ra[3];
        Sfe2[f] = rb[0] + rb[1] + rb[2] + rb[3];
      }
      BT[n * NK + t] = bits((__bf16)v);
    } else if (n < 384) {
      BT[n * NK + t] = 0;
    } else {
      const int c = n - 384;
      const float v = (c < C_) ? W2[t * C_ + c] : 0.f;
      W2T[c * D_ + t] = bits((__bf16)v);
    }
    return;
  }
  // fe-panel: P2f[f][t] = sum_k fe[f][k]*gamma[k]*W1[k][t]  -  Sfe_f * cs[t]/256
  {
    const int f = bid - 432;
    const float fv = fe[f * D_ + t];
    const float gv = gamma[t];
    fegl[t] = fv * gv;
    gl2[t]  = gv;
    float a = fv;
    #pragma unroll
    for (int m = 1; m < 64; m <<= 1) a += __shfl_xor(a, m);
    if (lane == 0) ra[wv] = a;
    __syncthreads();
    const float sfe = ra[0] + ra[1] + ra[2] + ra[3];
    float acc1 = 0.f, acc2 = 0.f;
    #pragma unroll 8
    for (int k = 0; k < 256; ++k) {
      const float w = W1[k * D_ + t];
      acc1 = __builtin_fmaf(fegl[k], w, acc1);
      acc2 = __builtin_fmaf(gl2[k],  w, acc2);
    }
    P2f[f * D_ + t] = __builtin_fmaf(-sfe * (1.f / 256.f), acc2, acc1);
  }
}

// ---------- gemmBk: PXg[MPAD x 384] = c @ BT (single bf16 product); Sc/Sc2 ----------
__global__ __launch_bounds__(256, 4) void gemmBk_kernel(
    const float* __restrict__ base, const float* __restrict__ joint,
    const unsigned short* __restrict__ BT,
    float* __restrict__ PXg, float* __restrict__ Sc, float* __restrict__ Sc2) {
  const int tid = threadIdx.x, lane = tid & 63, wave = tid >> 6;
  const int lrow = lane & 15, lgrp = lane >> 4;
  const int rb_ = blockIdx.x / 6, cb_ = blockIdx.x % 6;   // 74 x 6
  const int rowbase = rb_ * 64 + wave * 16;
  const int colbase = cb_ * 64;
  const int r = rowbase + lrow;
  const int bj = min(r, M_ - 1);
  const int b = bj / J_, j = bj - b * J_;
  const float* p1 = base + b * D_;
  const float* p2 = joint + j * D_;

  f32x4 acc[4] = {};
  float ssum = 0.f, ssq = 0.f;
  #pragma unroll
  for (int s8 = 0; s8 < 8; ++s8) {
    const int k0 = s8 * 32 + lgrp * 8;
    const float4 ca = *(const float4*)(p1 + k0);
    const float4 cb4 = *(const float4*)(p1 + k0 + 4);
    const float4 da = *(const float4*)(p2 + k0);
    const float4 db = *(const float4*)(p2 + k0 + 4);
    const float c[8] = {ca.x + da.x, ca.y + da.y, ca.z + da.z, ca.w + da.w,
                        cb4.x + db.x, cb4.y + db.y, cb4.z + db.z, cb4.w + db.w};
    bf16x8 ahi;
    #pragma unroll
    for (int e = 0; e < 8; ++e) ahi[e] = (__bf16)c[e];
    if (cb_ == 0) {
      #pragma unroll
      for (int e = 0; e < 8; ++e) { ssum += c[e]; ssq = __builtin_fmaf(c[e], c[e], ssq); }
    }
    bf16x8 bhi[4];
    #pragma unroll
    for (int nf = 0; nf < 4; ++nf)
      bhi[nf] = *(const bf16x8*)(BT + (size_t)(colbase + nf * 16 + lrow) * NK +
                                 lgrp * 8 + s8 * 32);
    #pragma unroll
    for (int nf = 0; nf < 4; ++nf)
      acc[nf] = __builtin_amdgcn_mfma_f32_16x16x32_bf16(ahi, bhi[nf], acc[nf], 0, 0, 0);
  }

  if (cb_ == 0) {
    ssum += __shfl_xor(ssum, 16); ssum += __shfl_xor(ssum, 32);
    ssq  += __shfl_xor(ssq, 16);  ssq  += __shfl_xor(ssq, 32);
    if (lgrp == 0 && r < M_) { Sc[r] = ssum; Sc2[r] = ssq; }
  }

  #pragma unroll
  for (int nf = 0; nf < 4; ++nf)
    #pragma unroll
    for (int r4 = 0; r4 < 4; ++r4)
      PXg[(size_t)(rowbase + lgrp * 4 + r4) * PXG + colbase + nf * 16 + lrow] =
          acc[nf][r4];
}

// ---------- mainC2: phase-C only, QB=6, (512,6) -> 3 blocks/CU ----------
#define QB2 6
#define GRIDC2 763
__global__ __launch_bounds__(512, 6) void mainC2_kernel(
    const float* __restrict__ PXg, const float* __restrict__ P2f,
    const float* __restrict__ bW1,
    const float* __restrict__ Sc, const float* __restrict__ Sc2,
    const float* __restrict__ Sfe, const float* __restrict__ Sfe2,
    const unsigned short* __restrict__ W2T, const float* __restrict__ b2,
    float* __restrict__ out) {
  __shared__ float pxl[QB2 * PXS];        // 9.3 KB
  __shared__ float bw[256];
  __shared__ float rstdl[QB2][128];
  __shared__ float Scl[QB2], Sc2l[QB2];
  __shared__ __align__(16) unsigned short w2l[4096];

  const int tid  = threadIdx.x;
  const int lane = tid & 63, wv = tid >> 6;
  const int lrow = lane & 15, lgrp = lane >> 4;
  const int bj0  = blockIdx.x * QB2;

  // ---- stage pxl (6x384), bw, w2l, Scl ----
  #pragma unroll
  for (int i = 0; i < 5; ++i) {
    const int idx = tid + i * 512;
    if (idx < QB2 * PXG) {
      const int q = idx / PXG;
      const int n = idx - q * PXG;
      pxl[q * PXS + n] = PXg[(size_t)(bj0 + q) * PXG + n];
    }
  }
  if (tid < 256) {
    bw[tid] = bW1[tid];
    const int rr = tid >> 4;
    const int b0 = tid * 32;
    const int sb = b0 ^ ((rr & 7) << 4);
    *(uint4*)((char*)w2l + sb)        = *(const uint4*)((const char*)W2T + b0);
    *(uint4*)((char*)w2l + (sb ^ 16)) = *(const uint4*)((const char*)W2T + b0 + 16);
  }
  if (tid < QB2) {
    const int bj = min(bj0 + tid, M_ - 1);
    Scl[tid] = Sc[bj];
    Sc2l[tid] = Sc2[bj];
  }
  __syncthreads();

  // ---- rstd per (q, f) ----
  #pragma unroll
  for (int i = 0; i < 2; ++i) {
    const int id2 = tid + i * 512;
    if (id2 < QB2 * 128) {
      const int q = id2 >> 7;
      const int fr = id2 & 127;
      const int fc = fr < F_ ? fr : F_ - 1;
      const float X = pxl[q * PXS + 256 + fc];
      const float mu = (Scl[q] + Sfe[fc]) * (1.f / 256.f);
      const float ms = __builtin_fmaf(2.f, X, Sc2l[q] + Sfe2[fc]) * (1.f / 256.f);
      rstdl[q][fr] = rsqrtf(ms - mu * mu + 1e-5f);
    }
  }
  __syncthreads();

  // ---- phase C: stage-split gelu per q (4 pairs in flight) + GEMM2 ----
  const int r0 = wv * 16 + lrow;
  const int f0 = r0 < F_ ? r0 : F_ - 1;
  float rs[QB2];
  #pragma unroll
  for (int q = 0; q < QB2; ++q) rs[q] = rstdl[q][r0];
  const float* __restrict__ q0p = P2f + f0 * D_ + lgrp * 8;

  f32x4 acc2[QB2] = {};
  #pragma unroll
  for (int s = 0; s < 8; ++s) {
    const int n0 = s * 32 + lgrp * 8;
    const float4 qa0 = *(const float4*)(q0p + s * 32);
    const float4 qa1 = *(const float4*)(q0p + s * 32 + 4);
    const bf16x8 w2f = *(const bf16x8*)((const char*)w2l +
        ((lrow * 512 + n0 * 2) ^ ((lrow & 7) << 4)));
    f32x2 QV[4], BV[4];
    QV[0].x = qa0.x; QV[0].y = qa0.y;
    QV[1].x = qa0.z; QV[1].y = qa0.w;
    QV[2].x = qa1.x; QV[2].y = qa1.y;
    QV[3].x = qa1.z; QV[3].y = qa1.w;
    #pragma unroll
    for (int ep = 0; ep < 4; ++ep) BV[ep] = *(const f32x2*)(&bw[n0 + 2 * ep]);

    #pragma unroll
    for (int q = 0; q < QB2; ++q) {
      f32x2 RS; RS.x = rs[q]; RS.y = rs[q];
      f32x2 U[4];
      #pragma unroll
      for (int ep = 0; ep < 4; ++ep) {
        const f32x2 P = *(const f32x2*)(&pxl[q * PXS + n0 + 2 * ep]);
        U[ep] = __builtin_elementwise_fma(RS, P + QV[ep], BV[ep]);
      }
      f32x2 E[4];
      #pragma unroll
      for (int i = 0; i < 4; ++i) {
        const f32x2 u = U[i];
        const f32x2 x2 = u * u;
        const f32x2 tt = u * (x2 * -0.1029432f + -2.3022082f);
        E[i].x = __builtin_amdgcn_exp2f(tt.x);
        E[i].y = __builtin_amdgcn_exp2f(tt.y);
      }
      bf16x8 af;
      #pragma unroll
      for (int i = 0; i < 4; ++i) {
        const f32x2 d = E[i] + 1.0f;
        f32x2 r;
        r.x = __builtin_amdgcn_rcpf(d.x);
        r.y = __builtin_amdgcn_rcpf(d.y);
        const f32x2 G = U[i] * r;
        af[i * 2]     = (__bf16)G.x;
        af[i * 2 + 1] = (__bf16)G.y;
      }
      acc2[q] = __builtin_amdgcn_mfma_f32_16x16x32_bf16(af, w2f, acc2[q], 0, 0, 0);
    }
  }

  // ---- epilogue ----
  if (lrow < C_) {
    const float bias = b2[lrow];
    const int f = wv * 16 + lgrp * 4;
    if (f < F_) {
      #pragma unroll
      for (int q = 0; q < QB2; ++q) {
        if (bj0 + q < M_) {
          float4 v;
          v.x = acc2[q][0] + bias;
          v.y = acc2[q][1] + bias;
          v.z = acc2[q][2] + bias;
          v.w = acc2[q][3] + bias;
          *(float4*)(out + (size_t)(bj0 + q) * (C_ * F_) + lrow * F_ + f) = v;
        }
      }
    }
  }
}

// ---------- fallback: R21's fused megaC (QB=9, (512,4), stage-split groups of 3) ----------
#define QB9 9
#define GRIDC9 509
__global__ __launch_bounds__(512, 4) void megaC_kernel(
    const float* __restrict__ base, const float* __restrict__ joint,
    const unsigned short* __restrict__ BT, const float* __restrict__ P2f,
    const float* __restrict__ bW1,
    const float* __restrict__ Sfe, const float* __restrict__ Sfe2,
    const unsigned short* __restrict__ W2T, const float* __restrict__ b2,
    float* __restrict__ out) {
  __shared__ float cl[16 * CLS];
  __shared__ float px[QB9 * PXS];
  __shared__ float bw[256];
  __shared__ float rstdl[QB9][128];
  __shared__ float Scl[QB9], Sc2l[QB9];
  __shared__ __align__(16) unsigned short w2l[4096];

  const int tid  = threadIdx.x;
  const int lane = tid & 63, wv = tid >> 6;
  const int lrow = lane & 15, lgrp = lane >> 4;
  const int bj0  = blockIdx.x * QB9;

  #pragma unroll
  for (int i = 0; i < 8; ++i) {
    const int idx = tid + i * 512;
    const int row = idx >> 8, col = idx & 255;
    float v = 0.f;
    if (row < QB9) {
      const int bj = min(bj0 + row, M_ - 1);
      const int b = bj / J_, j = bj - b * J_;
      v = base[b * D_ + col] + joint[j * D_ + col];
    }
    cl[row * CLS + col] = v;
  }
  if (tid < 256) {
    bw[tid] = bW1[tid];
    const int rr = tid >> 4;
    const int b0 = tid * 32;
    const int sb = b0 ^ ((rr & 7) << 4);
    *(uint4*)((char*)w2l + sb)        = *(const uint4*)((const char*)W2T + b0);
    *(uint4*)((char*)w2l + (sb ^ 16)) = *(const uint4*)((const char*)W2T + b0 + 16);
  }
  __syncthreads();

  for (int r = wv; r < QB9; r += 8) {
    const float4 v4 = *(const float4*)(cl + r * CLS + lane * 4);
    float s = v4.x + v4.y + v4.z + v4.w;
    float q = __builtin_fmaf(v4.x, v4.x,
              __builtin_fmaf(v4.y, v4.y,
              __builtin_fmaf(v4.z, v4.z, v4.w * v4.w)));
    #pragma unroll
    for (int m = 1; m < 64; m <<= 1) { s += __shfl_xor(s, m); q += __shfl_xor(q, m); }
    if (lane == 0) { Scl[r] = s; Sc2l[r] = q; }
  }

  {
    const int colbase = wv * 48;
    f32x4 acc[3] = {};
    #pragma unroll
    for (int s8 = 0; s8 < 8; ++s8) {
      const int k0 = s8 * 32 + lgrp * 8;
      const float4 c0 = *(const float4*)(cl + lrow * CLS + k0);
      const float4 c1 = *(const float4*)(cl + lrow * CLS + k0 + 4);
      const float cc[8] = {c0.x, c0.y, c0.z, c0.w, c1.x, c1.y, c1.z, c1.w};
      bf16x8 ahi;
      #pragma unroll
      for (int e = 0; e < 8; ++e) ahi[e] = (__bf16)cc[e];
      bf16x8 bhi[3];
      #pragma unroll
      for (int cf = 0; cf < 3; ++cf)
        bhi[cf] = *(const bf16x8*)(BT + (size_t)(colbase + cf * 16 + lrow) * NK +
                                   lgrp * 8 + s8 * 32);
      #pragma unroll
      for (int cf = 0; cf < 3; ++cf)
        acc[cf] = __builtin_amdgcn_mfma_f32_16x16x32_bf16(ahi, bhi[cf], acc[cf], 0, 0, 0);
    }
    #pragma unroll
    for (int cf = 0; cf < 3; ++cf)
      #pragma unroll
      for (int r4 = 0; r4 < 4; ++r4) {
        const int row = lgrp * 4 + r4;
        if (row < QB9)
          px[row * PXS + colbase + cf * 16 + lrow] = acc[cf][r4];
      }
  }
  __syncthreads();

  #pragma unroll
  for (int i = 0; i < 3; ++i) {
    const int id2 = tid + i * 512;
    if (id2 < QB9 * 128) {
      const int q = id2 >> 7;
      const int fr = id2 & 127;
      const int fc = fr < F_ ? fr : F_ - 1;
      const float X = px[q * PXS + 256 + fc];
      const float mu = (Scl[q] + Sfe[fc]) * (1.f / 256.f);
      const float ms = __builtin_fmaf(2.f, X, Sc2l[q] + Sfe2[fc]) * (1.f / 256.f);
      rstdl[q][fr] = rsqrtf(ms - mu * mu + 1e-5f);
    }
  }
  __syncthreads();

  const int r0 = wv * 16 + lrow;
  const int f0 = r0 < F_ ? r0 : F_ - 1;
  float rs[QB9];
  #pragma unroll
  for (int q = 0; q < QB9; ++q) rs[q] = rstdl[q][r0];
  const float* __restrict__ q0p = P2f + f0 * D_ + lgrp * 8;

  f32x4 acc2[QB9] = {};
  #pragma unroll
  for (int s = 0; s < 8; ++s) {
    const int n0 = s * 32 + lgrp * 8;
    const float4 qa0 = *(const float4*)(q0p + s * 32);
    const float4 qa1 = *(const float4*)(q0p + s * 32 + 4);
    const bf16x8 w2f = *(const bf16x8*)((const char*)w2l +
        ((lrow * 512 + n0 * 2) ^ ((lrow & 7) << 4)));
    f32x2 QV[4], BV[4];
    QV[0].x = qa0.x; QV[0].y = qa0.y;
    QV[1].x = qa0.z; QV[1].y = qa0.w;
    QV[2].x = qa1.x; QV[2].y = qa1.y;
    QV[3].x = qa1.z; QV[3].y = qa1.w;
    #pragma unroll
    for (int ep = 0; ep < 4; ++ep) BV[ep] = *(const f32x2*)(&bw[n0 + 2 * ep]);

    #pragma unroll
    for (int g = 0; g < QB9; g += 3) {
      f32x2 U[12];
      #pragma unroll
      for (int qq = 0; qq < 3; ++qq) {
        f32x2 RS; RS.x = rs[g + qq]; RS.y = rs[g + qq];
        #pragma unroll
        for (int ep = 0; ep < 4; ++ep) {
          const f32x2 P = *(const f32x2*)(&px[(g + qq) * PXS + n0 + 2 * ep]);
          U[qq * 4 + ep] = __builtin_elementwise_fma(RS, P + QV[ep], BV[ep]);
        }
      }
      f32x2 E[12];
      #pragma unroll
      for (int i = 0; i < 12; ++i) {
        const f32x2 u = U[i];
        const f32x2 x2 = u * u;
        const f32x2 tt = u * (x2 * -0.1029432f + -2.3022082f);
        E[i].x = __builtin_amdgcn_exp2f(tt.x);
        E[i].y = __builtin_amdgcn_exp2f(tt.y);
      }
      bf16x8 af[3];
      #pragma unroll
      for (int i = 0; i < 12; ++i) {
        const f32x2 d = E[i] + 1.0f;
        f32x2 r;
        r.x = __builtin_amdgcn_rcpf(d.x);
        r.y = __builtin_amdgcn_rcpf(d.y);
        const f32x2 G = U[i] * r;
        af[i >> 2][(i & 3) * 2]     = (__bf16)G.x;
        af[i >> 2][(i & 3) * 2 + 1] = (__bf16)G.y;
      }
      #pragma unroll
      for (int qq = 0; qq < 3; ++qq)
        acc2[g + qq] =
            __builtin_amdgcn_mfma_f32_16x16x32_bf16(af[qq], w2f, acc2[g + qq], 0, 0, 0);
    }
  }

  if (lrow < C_) {
    const float bias = b2[lrow];
    const int f = wv * 16 + lgrp * 4;
    if (f < F_) {
      #pragma unroll
      for (int q = 0; q < QB9; ++q) {
        if (bj0 + q < M_) {
          float4 v;
          v.x = acc2[q][0] + bias;
          v.y = acc2[q][1] + bias;
          v.z = acc2[q][2] + bias;
          v.w = acc2[q][3] + bias;
          *(float4*)(out + (size_t)(bj0 + q) * (C_ * F_) + lrow * F_ + f) = v;
        }
      }
    }
  }
}

extern "C" void kernel_launch(void* const* d_in, const int* in_sizes, int n_in,
                              void* d_out, int out_size, void* d_ws, size_t ws_size,
                              hipStream_t stream) {
  const float* z     = (const float*)d_in[0];
  const float* Wl    = (const float*)d_in[1];
  const float* bl    = (const float*)d_in[2];
  const float* joint = (const float*)d_in[3];
  const float* fe    = (const float*)d_in[4];
  const float* gamma = (const float*)d_in[5];
  const float* beta  = (const float*)d_in[6];
  const float* W1    = (const float*)d_in[7];
  const float* b1    = (const float*)d_in[8];
  const float* W2    = (const float*)d_in[9];
  const float* b2    = (const float*)d_in[10];
  float* out = (float*)d_out;

  char* ws = (char*)d_ws;
  float*          base  = (float*)(ws + 0);               // 32 KB
  unsigned short* W2T   = (unsigned short*)(ws + 32768);  // 8 KB
  float*          bW1   = (float*)(ws + 40960);           // 1 KB
  float*          Sfe   = (float*)(ws + 41984);           // 0.5 KB
  float*          Sfe2  = (float*)(ws + 42496);           // 0.5 KB
  float*          Sc    = (float*)(ws + 49152);           // 18.9 KB
  float*          Sc2   = (float*)(ws + 69632);           // 18.9 KB
  float*          P2f   = (float*)(ws + 98304);           // 123 KB
  unsigned short* BT    = (unsigned short*)(ws + 262144); // 192 KB
  float*          PXg   = (float*)(ws + 524288);          // 7.28 MB

  prep_kernel<<<552, 256, 0, stream>>>(z, Wl, bl, W1, gamma, beta, b1, fe, W2,
                                       base, BT, bW1, Sfe, Sfe2, W2T, P2f);

  hipFuncAttributes a{};
  const bool ok = (hipFuncGetAttributes(&a, (const void*)mainC2_kernel) == hipSuccess) &&
                  (a.localSizeBytes == 0);

  if (ok) {
    gemmBk_kernel<<<444, 256, 0, stream>>>(base, joint, BT, PXg, Sc, Sc2);
    mainC2_kernel<<<GRIDC2, 512, 0, stream>>>(PXg, P2f, bW1, Sc, Sc2, Sfe, Sfe2,
                                              W2T, b2, out);
  } else {
    megaC_kernel<<<GRIDC9, 512, 0, stream>>>(base, joint, BT, P2f, bW1,
                                             Sfe, Sfe2, W2T, b2, out);
  }
}

// Round 23
// 68.662 us; speedup vs baseline: 1.1090x; 1.1090x over previous
//
#include <hip/hip_runtime.h>
#include <hip/hip_bf16.h>

typedef __bf16 bf16x8 __attribute__((ext_vector_type(8)));
typedef float  f32x4  __attribute__((ext_vector_type(4)));
typedef float  f32x2  __attribute__((ext_vector_type(2)));

#define B_  32
#define J_  143
#define F_  120
#define D_  256
#define L_  512
#define C_  13
#define M_  4576      // B_*J_
#define NK  256       // BT col stride (hi-only bf16)
#define QB  9         // bj per megaC block
#define GRIDC 509     // ceil(4576/9)
#define CLS 260       // cl row stride (f32)
#define PXS 388       // px row stride (f32, 16B-aligned rows)

static __device__ __forceinline__ unsigned short bits(__bf16 h) {
  return __builtin_bit_cast(unsigned short, h);
}

// ---------- prep (552 blocks) — unchanged from R17/R21 ----------
__global__ __launch_bounds__(256) void prep_kernel(
    const float* __restrict__ z, const float* __restrict__ Wl,
    const float* __restrict__ bl, const float* __restrict__ W1,
    const float* __restrict__ gamma, const float* __restrict__ beta,
    const float* __restrict__ b1, const float* __restrict__ fe,
    const float* __restrict__ W2,
    float* __restrict__ base, unsigned short* __restrict__ BT,
    float* __restrict__ bW1, float* __restrict__ Sfe, float* __restrict__ Sfe2,
    unsigned short* __restrict__ W2T, float* __restrict__ P2f) {
  const int t = threadIdx.x, bid = blockIdx.x;
  const int lane = t & 63, wv = t >> 6;
  __shared__ float zs[L_];
  __shared__ float ra[4], rb[4];
  __shared__ float fegl[256], gl2[256];

  if (bid < 32) {
    zs[t]       = z[bid * L_ + t];
    zs[t + 256] = z[bid * L_ + t + 256];
    __syncthreads();
    float acc = 0.f;
    #pragma unroll 32
    for (int k = 0; k < L_; ++k) acc = __builtin_fmaf(zs[k], Wl[k * D_ + t], acc);
    base[bid * D_ + t] = acc + bl[t];
    return;
  }
  if (bid < 432) {
    const int n = bid - 32;
    if (n < 256) {
      const float w1v = W1[t * D_ + n];
      float a = gamma[t] * w1v;
      float b = beta[t] * w1v;
      const float wg = a;
      #pragma unroll
      for (int m = 1; m < 64; m <<= 1) { a += __shfl_xor(a, m); b += __shfl_xor(b, m); }
      if (lane == 0) { ra[wv] = a; rb[wv] = b; }
      __syncthreads();
      const float cs = ra[0] + ra[1] + ra[2] + ra[3];
      if (t == 0) bW1[n] = rb[0] + rb[1] + rb[2] + rb[3] + b1[n];
      const float m = __builtin_fmaf(cs, -1.f / 256.f, wg);
      BT[n * NK + t] = bits((__bf16)m);
    } else if (n < 376) {
      const int f = n - 256;
      const float v = fe[f * D_ + t];
      float a = v, b = v * v;
      #pragma unroll
      for (int m = 1; m < 64; m <<= 1) { a += __shfl_xor(a, m); b += __shfl_xor(b, m); }
      if (lane == 0) { ra[wv] = a; rb[wv] = b; }
      __syncthreads();
      if (t == 0) {
        Sfe[f]  = ra[0] + ra[1] + ra[2] + ra[3];
        Sfe2[f] = rb[0] + rb[1] + rb[2] + rb[3];
      }
      BT[n * NK + t] = bits((__bf16)v);
    } else if (n < 384) {
      BT[n * NK + t] = 0;
    } else {
      const int c = n - 384;
      const float v = (c < C_) ? W2[t * C_ + c] : 0.f;
      W2T[c * D_ + t] = bits((__bf16)v);
    }
    return;
  }
  // fe-panel: P2f[f][t] = sum_k fe[f][k]*gamma[k]*W1[k][t]  -  Sfe_f * cs[t]/256
  {
    const int f = bid - 432;
    const float fv = fe[f * D_ + t];
    const float gv = gamma[t];
    fegl[t] = fv * gv;
    gl2[t]  = gv;
    float a = fv;
    #pragma unroll
    for (int m = 1; m < 64; m <<= 1) a += __shfl_xor(a, m);
    if (lane == 0) ra[wv] = a;
    __syncthreads();
    const float sfe = ra[0] + ra[1] + ra[2] + ra[3];
    float acc1 = 0.f, acc2 = 0.f;
    #pragma unroll 8
    for (int k = 0; k < 256; ++k) {
      const float w = W1[k * D_ + t];
      acc1 = __builtin_fmaf(fegl[k], w, acc1);
      acc2 = __builtin_fmaf(gl2[k],  w, acc2);
    }
    P2f[f * D_ + t] = __builtin_fmaf(-sfe * (1.f / 256.f), acc2, acc1);
  }
}

// ---------- megaC: 512 threads, 9 bj per block; stage-split phase C, b128 LDS reads ----------
__global__ __launch_bounds__(512, 4) void megaC_kernel(
    const float* __restrict__ base, const float* __restrict__ joint,
    const unsigned short* __restrict__ BT, const float* __restrict__ P2f,
    const float* __restrict__ bW1,
    const float* __restrict__ Sfe, const float* __restrict__ Sfe2,
    const unsigned short* __restrict__ W2T, const float* __restrict__ b2,
    float* __restrict__ out) {
  __shared__ float cl[16 * CLS];
  __shared__ float px[QB * PXS];
  __shared__ float bw[256];
  __shared__ float rstdl[QB][128];
  __shared__ float Scl[QB], Sc2l[QB];
  __shared__ __align__(16) unsigned short w2l[4096];

  const int tid  = threadIdx.x;
  const int lane = tid & 63, wv = tid >> 6;
  const int lrow = lane & 15, lgrp = lane >> 4;
  const int bj0  = blockIdx.x * QB;

  // ---- phase A: stage c rows, bw, w2l ----
  #pragma unroll
  for (int i = 0; i < 8; ++i) {
    const int idx = tid + i * 512;
    const int row = idx >> 8, col = idx & 255;
    float v = 0.f;
    if (row < QB) {
      const int bj = min(bj0 + row, M_ - 1);
      const int b = bj / J_, j = bj - b * J_;
      v = base[b * D_ + col] + joint[j * D_ + col];
    }
    cl[row * CLS + col] = v;
  }
  if (tid < 256) {
    bw[tid] = bW1[tid];
    const int rr = tid >> 4;
    const int b0 = tid * 32;
    const int sb = b0 ^ ((rr & 7) << 4);
    *(uint4*)((char*)w2l + sb)        = *(const uint4*)((const char*)W2T + b0);
    *(uint4*)((char*)w2l + (sb ^ 16)) = *(const uint4*)((const char*)W2T + b0 + 16);
  }
  __syncthreads();

  // ---- Sc/Sc2 per c-row ----
  for (int r = wv; r < QB; r += 8) {
    const float4 v4 = *(const float4*)(cl + r * CLS + lane * 4);
    float s = v4.x + v4.y + v4.z + v4.w;
    float q = __builtin_fmaf(v4.x, v4.x,
              __builtin_fmaf(v4.y, v4.y,
              __builtin_fmaf(v4.z, v4.z, v4.w * v4.w)));
    #pragma unroll
    for (int m = 1; m < 64; m <<= 1) { s += __shfl_xor(s, m); q += __shfl_xor(q, m); }
    if (lane == 0) { Scl[r] = s; Sc2l[r] = q; }
  }

  // ---- phase B: px[QB][384] = cl @ BT (single bf16 product), wave owns 48 cols ----
  {
    const int colbase = wv * 48;
    f32x4 acc[3] = {};
    #pragma unroll
    for (int s8 = 0; s8 < 8; ++s8) {
      const int k0 = s8 * 32 + lgrp * 8;
      const float4 c0 = *(const float4*)(cl + lrow * CLS + k0);
      const float4 c1 = *(const float4*)(cl + lrow * CLS + k0 + 4);
      const float cc[8] = {c0.x, c0.y, c0.z, c0.w, c1.x, c1.y, c1.z, c1.w};
      bf16x8 ahi;
      #pragma unroll
      for (int e = 0; e < 8; ++e) ahi[e] = (__bf16)cc[e];
      bf16x8 bhi[3];
      #pragma unroll
      for (int cf = 0; cf < 3; ++cf)
        bhi[cf] = *(const bf16x8*)(BT + (size_t)(colbase + cf * 16 + lrow) * NK +
                                   lgrp * 8 + s8 * 32);
      #pragma unroll
      for (int cf = 0; cf < 3; ++cf)
        acc[cf] = __builtin_amdgcn_mfma_f32_16x16x32_bf16(ahi, bhi[cf], acc[cf], 0, 0, 0);
    }
    #pragma unroll
    for (int cf = 0; cf < 3; ++cf)
      #pragma unroll
      for (int r4 = 0; r4 < 4; ++r4) {
        const int row = lgrp * 4 + r4;
        if (row < QB)
          px[row * PXS + colbase + cf * 16 + lrow] = acc[cf][r4];
      }
  }
  __syncthreads();

  // ---- rstd per (q, f) ----
  #pragma unroll
  for (int i = 0; i < 3; ++i) {
    const int id2 = tid + i * 512;
    if (id2 < QB * 128) {
      const int q = id2 >> 7;
      const int fr = id2 & 127;
      const int fc = fr < F_ ? fr : F_ - 1;
      const float X = px[q * PXS + 256 + fc];
      const float mu = (Scl[q] + Sfe[fc]) * (1.f / 256.f);
      const float ms = __builtin_fmaf(2.f, X, Sc2l[q] + Sfe2[fc]) * (1.f / 256.f);
      rstdl[q][fr] = rsqrtf(ms - mu * mu + 1e-5f);
    }
  }
  __syncthreads();

  // ---- phase C: stage-split gelu (groups of 3 q = 12 pairs in flight) + GEMM2 ----
  const int r0 = wv * 16 + lrow;
  const int f0 = r0 < F_ ? r0 : F_ - 1;
  float rs[QB];
  #pragma unroll
  for (int q = 0; q < QB; ++q) rs[q] = rstdl[q][r0];
  const float* __restrict__ q0p = P2f + f0 * D_ + lgrp * 8;

  f32x4 acc2[QB] = {};
  #pragma unroll
  for (int s = 0; s < 8; ++s) {
    const int n0 = s * 32 + lgrp * 8;
    const float4 qa0 = *(const float4*)(q0p + s * 32);
    const float4 qa1 = *(const float4*)(q0p + s * 32 + 4);
    const bf16x8 w2f = *(const bf16x8*)((const char*)w2l +
        ((lrow * 512 + n0 * 2) ^ ((lrow & 7) << 4)));
    f32x2 QV[4], BV[4];
    QV[0].x = qa0.x; QV[0].y = qa0.y;
    QV[1].x = qa0.z; QV[1].y = qa0.w;
    QV[2].x = qa1.x; QV[2].y = qa1.y;
    QV[3].x = qa1.z; QV[3].y = qa1.w;
    {
      // b128 bw reads (2 instead of 4)
      const float4 b0 = *(const float4*)(&bw[n0]);
      const float4 b1 = *(const float4*)(&bw[n0 + 4]);
      BV[0].x = b0.x; BV[0].y = b0.y;
      BV[1].x = b0.z; BV[1].y = b0.w;
      BV[2].x = b1.x; BV[2].y = b1.y;
      BV[3].x = b1.z; BV[3].y = b1.w;
    }

    #pragma unroll
    for (int g = 0; g < QB; g += 3) {
      // stage 1: 12 independent U's, px read as b128 (2 loads per q)
      f32x2 U[12];
      #pragma unroll
      for (int qq = 0; qq < 3; ++qq) {
        f32x2 RS; RS.x = rs[g + qq]; RS.y = rs[g + qq];
        const float4 p0 = *(const float4*)(&px[(g + qq) * PXS + n0]);
        const float4 p1 = *(const float4*)(&px[(g + qq) * PXS + n0 + 4]);
        f32x2 P[4];
        P[0].x = p0.x; P[0].y = p0.y;
        P[1].x = p0.z; P[1].y = p0.w;
        P[2].x = p1.x; P[2].y = p1.y;
        P[3].x = p1.z; P[3].y = p1.w;
        #pragma unroll
        for (int ep = 0; ep < 4; ++ep)
          U[qq * 4 + ep] = __builtin_elementwise_fma(RS, P[ep] + QV[ep], BV[ep]);
      }
      // stage 2: 24 independent exp2's
      f32x2 E[12];
      #pragma unroll
      for (int i = 0; i < 12; ++i) {
        const f32x2 u = U[i];
        const f32x2 x2 = u * u;
        const f32x2 tt = u * (x2 * -0.1029432f + -2.3022082f);
        E[i].x = __builtin_amdgcn_exp2f(tt.x);
        E[i].y = __builtin_amdgcn_exp2f(tt.y);
      }
      // stage 3: 24 independent rcp's + finish, pack af
      bf16x8 af[3];
      #pragma unroll
      for (int i = 0; i < 12; ++i) {
        const f32x2 d = E[i] + 1.0f;
        f32x2 r;
        r.x = __builtin_amdgcn_rcpf(d.x);
        r.y = __builtin_amdgcn_rcpf(d.y);
        const f32x2 G = U[i] * r;
        af[i >> 2][(i & 3) * 2]     = (__bf16)G.x;
        af[i >> 2][(i & 3) * 2 + 1] = (__bf16)G.y;
      }
      // stage 4: 3 MFMAs
      #pragma unroll
      for (int qq = 0; qq < 3; ++qq)
        acc2[g + qq] =
            __builtin_amdgcn_mfma_f32_16x16x32_bf16(af[qq], w2f, acc2[g + qq], 0, 0, 0);
    }
  }

  // ---- epilogue: acc2[q][r4] is (c = lrow, f = wv*16 + lgrp*4 + r4) ----
  if (lrow < C_) {
    const float bias = b2[lrow];
    const int f = wv * 16 + lgrp * 4;
    if (f < F_) {
      #pragma unroll
      for (int q = 0; q < QB; ++q) {
        if (bj0 + q < M_) {
          float4 v;
          v.x = acc2[q][0] + bias;
          v.y = acc2[q][1] + bias;
          v.z = acc2[q][2] + bias;
          v.w = acc2[q][3] + bias;
          *(float4*)(out + (size_t)(bj0 + q) * (C_ * F_) + lrow * F_ + f) = v;
        }
      }
    }
  }
}

extern "C" void kernel_launch(void* const* d_in, const int* in_sizes, int n_in,
                              void* d_out, int out_size, void* d_ws, size_t ws_size,
                              hipStream_t stream) {
  const float* z     = (const float*)d_in[0];
  const float* Wl    = (const float*)d_in[1];
  const float* bl    = (const float*)d_in[2];
  const float* joint = (const float*)d_in[3];
  const float* fe    = (const float*)d_in[4];
  const float* gamma = (const float*)d_in[5];
  const float* beta  = (const float*)d_in[6];
  const float* W1    = (const float*)d_in[7];
  const float* b1    = (const float*)d_in[8];
  const float* W2    = (const float*)d_in[9];
  const float* b2    = (const float*)d_in[10];
  float* out = (float*)d_out;

  char* ws = (char*)d_ws;
  float*          base  = (float*)(ws + 0);               // 32 KB
  unsigned short* W2T   = (unsigned short*)(ws + 32768);  // 8 KB
  float*          bW1   = (float*)(ws + 40960);           // 1 KB
  float*          Sfe   = (float*)(ws + 41984);           // 0.5 KB
  float*          Sfe2  = (float*)(ws + 42496);           // 0.5 KB
  float*          P2f   = (float*)(ws + 65536);           // 123 KB
  unsigned short* BT    = (unsigned short*)(ws + 262144); // 192 KB

  prep_kernel<<<552, 256, 0, stream>>>(z, Wl, bl, W1, gamma, beta, b1, fe, W2,
                                       base, BT, bW1, Sfe, Sfe2, W2T, P2f);
  megaC_kernel<<<GRIDC, 512, 0, stream>>>(base, joint, BT, P2f, bW1,
                                          Sfe, Sfe2, W2T, b2, out);
}